// Round 1
// baseline (923.056 us; speedup 1.0000x reference)
//
#include <hip/hip_runtime.h>

// GenLSTM: B=8192, T=256 (255 steps), noise=8, seq_dim=4, HID=64, gates=256.
// Design: 1 wave (64 thr) per block, 16 batch rows per block, 512 blocks.
// All weights fp16-transposed in LDS (K-contiguous for ds_read_b128 B-frags).
// fp16 MFMA 16x16x32, fp32 accum; c/h/cumsum state fp32 in regs (C-layout).
// No barriers in the t-loop: LDS buffers are wave-private, same-wave DS ops
// are in-order. LDS/block = 79,616 B -> 2 blocks/CU (512 blocks = 2x256 CU).

typedef _Float16 h8 __attribute__((ext_vector_type(8)));
typedef float f4 __attribute__((ext_vector_type(4)));

#define MFMA(a, b, c) __builtin_amdgcn_mfma_f32_16x16x32_f16(a, b, c, 0, 0, 0)

constexpr int SEQ = 256, STEPS = 255, ND = 8, SD = 4, HID = 64, G4 = 256;
constexpr int UST = 104;  // u row stride (fp16): 16B-aligned, 2-way bank alias (free)
constexpr int YST = 72;   // y row stride

__device__ __forceinline__ float sigf(float x) {
    return __builtin_amdgcn_rcpf(1.0f + __expf(-x));
}
__device__ __forceinline__ float tanh_(float x) {
    return 2.0f * __builtin_amdgcn_rcpf(1.0f + __expf(-2.0f * x)) - 1.0f;
}

__global__ __launch_bounds__(64) void genlstm_kernel(
    const float* __restrict__ noise, const float* __restrict__ Wx,
    const float* __restrict__ Wh, const float* __restrict__ b,
    const float* __restrict__ W1, const float* __restrict__ b1,
    const float* __restrict__ W2, const float* __restrict__ b2,
    const float* __restrict__ W3, const float* __restrict__ b3,
    float* __restrict__ out)
{
    // u layout (K=96): [0..3]=x, [4..11]=noise, [12..15]=0, [16..79]=h, [80..95]=0
    __shared__ _Float16 Wt[G4 * UST];    // 53248 B  (rows: combined [Wx;pad;Wh;pad], transposed)
    __shared__ _Float16 W1t[HID * YST];  //  9216 B
    __shared__ _Float16 W2t[HID * YST];  //  9216 B
    __shared__ _Float16 W3t[16 * YST];   //  2304 B  (cols 4..15 zero)
    __shared__ _Float16 U[16 * UST];     //  3328 B  (per-wave state buffer)
    __shared__ _Float16 Y[16 * YST];     //  2304 B  (y1 then y2, reused)

    const int lane = threadIdx.x;
    const int row0 = blockIdx.x * 16;
    const int col  = lane & 15;   // A-frag row m / B-frag col n / C col
    const int quad = lane >> 4;
    const int q8   = quad * 8;

    // ---- stage weights fp32 -> fp16, K-contiguous (transposed) ----
    for (int rr = 0; rr < 4; ++rr) {
        const int n = rr * 64 + lane;
        const int base = n * UST;
        for (int k = 0; k < UST; ++k) {
            float v = 0.0f;
            if (k < 12) v = Wx[k * G4 + n];
            else if (k >= 16 && k < 80) v = Wh[(k - 16) * G4 + n];
            Wt[base + k] = (_Float16)v;
        }
    }
    for (int k = 0; k < HID; ++k) {
        W1t[lane * YST + k] = (_Float16)W1[k * HID + lane];
        W2t[lane * YST + k] = (_Float16)W2[k * HID + lane];
    }
    if (lane < 16)
        for (int k = 0; k < HID; ++k)
            W3t[lane * YST + k] = (_Float16)(lane < 4 ? W3[k * SD + lane] : 0.0f);
    for (int i = lane; i < 16 * UST; i += 64) U[i] = (_Float16)0.0f;  // x0=h0=0, pads=0

    // stage noise for t=0: lane -> (row = lane>>2, 2 floats at 4 + (lane&3)*2)
    const int nrow = lane >> 2, ncc = (lane & 3) * 2;
    {
        float2 nz = *(const float2*)(noise + ((size_t)(row0 + nrow) * SEQ + 0) * ND + ncc);
        U[nrow * UST + 4 + ncc] = (_Float16)nz.x;
        U[nrow * UST + 5 + ncc] = (_Float16)nz.y;
    }
    // out[:, 0, :] = 0 (cumsum starts at x0 = 0)
    if (lane < 16) {
        float4 z; z.x = z.y = z.z = z.w = 0.0f;
        *(float4*)(out + ((size_t)(row0 + lane) * SEQ) * SD) = z;
    }
    __syncthreads();

    // per-lane bias registers (bias depends only on output col)
    float bz[16];
    #pragma unroll
    for (int tl = 0; tl < 16; ++tl) bz[tl] = b[tl * 16 + col];
    float b1r[4], b2r[4];
    #pragma unroll
    for (int nt = 0; nt < 4; ++nt) { b1r[nt] = b1[nt * 16 + col]; b2r[nt] = b2[nt * 16 + col]; }
    const float b3v = (col < 4) ? b3[col] : 0.0f;

    float c[4][4];   // cell state, C-layout: c[nt][r] = C(row=quad*4+r, hidcol=nt*16+col)
    #pragma unroll
    for (int a_ = 0; a_ < 4; ++a_)
        #pragma unroll
        for (int r = 0; r < 4; ++r) c[a_][r] = 0.0f;
    float run[4] = {0.0f, 0.0f, 0.0f, 0.0f};  // cumsum (valid on col<4 lanes)

    const _Float16* Um = U + col * UST;
    const _Float16* Ym = Y + col * YST;

    #pragma unroll 1
    for (int t = 0; t < STEPS; ++t) {
        // prefetch next step's noise early (hide global latency under MFMA)
        float2 nz; nz.x = 0.0f; nz.y = 0.0f;
        if (t + 1 < STEPS)
            nz = *(const float2*)(noise + ((size_t)(row0 + nrow) * SEQ + (t + 1)) * ND + ncc);

        // A-frags of u = [x, noise, 0, h, 0]  (K=96 -> 3 k-steps)
        h8 a0 = *(const h8*)(Um + q8);
        h8 a1 = *(const h8*)(Um + 32 + q8);
        h8 a2 = *(const h8*)(Um + 64 + q8);

        // z = u @ [Wx;Wh] + b ; gates i,f,g,o = z cols [0:64,64:128,128:192,192:256]
        #pragma unroll
        for (int nt = 0; nt < 4; ++nt) {
            f4 aI = {bz[nt],      bz[nt],      bz[nt],      bz[nt]};
            f4 aF = {bz[4 + nt],  bz[4 + nt],  bz[4 + nt],  bz[4 + nt]};
            f4 aG = {bz[8 + nt],  bz[8 + nt],  bz[8 + nt],  bz[8 + nt]};
            f4 aO = {bz[12 + nt], bz[12 + nt], bz[12 + nt], bz[12 + nt]};
            const _Float16* wI = Wt + (0   + nt * 16 + col) * UST + q8;
            const _Float16* wF = Wt + (64  + nt * 16 + col) * UST + q8;
            const _Float16* wG = Wt + (128 + nt * 16 + col) * UST + q8;
            const _Float16* wO = Wt + (192 + nt * 16 + col) * UST + q8;
            #pragma unroll
            for (int s = 0; s < 3; ++s) {
                h8 as = (s == 0) ? a0 : (s == 1) ? a1 : a2;
                aI = MFMA(as, *(const h8*)(wI + 32 * s), aI);
                aF = MFMA(as, *(const h8*)(wF + 32 * s), aF);
                aG = MFMA(as, *(const h8*)(wG + 32 * s), aG);
                aO = MFMA(as, *(const h8*)(wO + 32 * s), aO);
            }
            #pragma unroll
            for (int r = 0; r < 4; ++r) {
                float I  = sigf(aI[r]);
                float F  = sigf(aF[r]);
                float Gv = tanh_(aG[r]);
                float O  = sigf(aO[r]);
                float cn = F * c[nt][r] + I * Gv;
                c[nt][r] = cn;
                float H  = O * tanh_(cn);
                // stage new h into u cols 16..79 (old h A-frags already in regs)
                U[(quad * 4 + r) * UST + 16 + nt * 16 + col] = (_Float16)H;
            }
        }

        // y1 = relu(h @ W1 + b1)
        h8 hh0 = *(const h8*)(Um + 16 + q8);
        h8 hh1 = *(const h8*)(Um + 48 + q8);
        #pragma unroll
        for (int nt = 0; nt < 4; ++nt) {
            f4 acc = {b1r[nt], b1r[nt], b1r[nt], b1r[nt]};
            const _Float16* w = W1t + (nt * 16 + col) * YST + q8;
            acc = MFMA(hh0, *(const h8*)(w), acc);
            acc = MFMA(hh1, *(const h8*)(w + 32), acc);
            #pragma unroll
            for (int r = 0; r < 4; ++r)
                Y[(quad * 4 + r) * YST + nt * 16 + col] = (_Float16)fmaxf(acc[r], 0.0f);
        }
        // y2 = relu(y1 @ W2 + b2)  (A-frags read before Y is overwritten)
        h8 ya0 = *(const h8*)(Ym + q8);
        h8 ya1 = *(const h8*)(Ym + 32 + q8);
        #pragma unroll
        for (int nt = 0; nt < 4; ++nt) {
            f4 acc = {b2r[nt], b2r[nt], b2r[nt], b2r[nt]};
            const _Float16* w = W2t + (nt * 16 + col) * YST + q8;
            acc = MFMA(ya0, *(const h8*)(w), acc);
            acc = MFMA(ya1, *(const h8*)(w + 32), acc);
            #pragma unroll
            for (int r = 0; r < 4; ++r)
                Y[(quad * 4 + r) * YST + nt * 16 + col] = (_Float16)fmaxf(acc[r], 0.0f);
        }
        // x_new = y2 @ W3 + b3  (N=4 padded to 16)
        h8 yb0 = *(const h8*)(Ym + q8);
        h8 yb1 = *(const h8*)(Ym + 32 + q8);
        f4 xa = {b3v, b3v, b3v, b3v};
        {
            const _Float16* w = W3t + col * YST + q8;
            xa = MFMA(yb0, *(const h8*)(w), xa);
            xa = MFMA(yb1, *(const h8*)(w + 32), xa);
        }
        if (col < 4) {
            #pragma unroll
            for (int r = 0; r < 4; ++r) {
                run[r] += xa[r];
                out[((size_t)(row0 + quad * 4 + r) * SEQ + (t + 1)) * SD + col] = run[r];
                U[(quad * 4 + r) * UST + col] = (_Float16)xa[r];  // x for next step
            }
        }
        // stage next step's noise
        U[nrow * UST + 4 + ncc] = (_Float16)nz.x;
        U[nrow * UST + 5 + ncc] = (_Float16)nz.y;
    }
}

extern "C" void kernel_launch(void* const* d_in, const int* in_sizes, int n_in,
                              void* d_out, int out_size, void* d_ws, size_t ws_size,
                              hipStream_t stream) {
    genlstm_kernel<<<512, 64, 0, stream>>>(
        (const float*)d_in[0], (const float*)d_in[1], (const float*)d_in[2],
        (const float*)d_in[3], (const float*)d_in[4], (const float*)d_in[5],
        (const float*)d_in[6], (const float*)d_in[7], (const float*)d_in[8],
        (const float*)d_in[9], (float*)d_out);
}

// Round 2
// 425.154 us; speedup vs baseline: 2.1711x; 2.1711x over previous
//
#include <hip/hip_runtime.h>

// GenLSTM: B=8192, T=256 (255 steps), noise=8, seq_dim=4, HID=64, gates=256.
// R2 design: block = 4 waves (256 thr) cooperating on 16 batch rows, 512 blocks
// -> 2048 waves = 8 waves/CU (vs 512 waves = 2/CU in R1, which was latency-bound
// at 6% occupancy). Wave w owns hidden cols [16w,16w+16): gate matmul N=256
// split 4x64 (12 MFMAs/wave), y1/y2 split 4x16 (2 MFMAs each); wave 0 does the
// N=4 x-stage + cumsum + store; wave 1 prefetches next-step noise.
// ALL weight B-frags in VGPRs (~72/lane) -> no LDS weight reads (R1's 3.9e7
// bank-conflict cycles came from 66 strided ds_read_b128/step of weights).
// Shared state u (x|noise|h) double-buffered in LDS (no WAR race), y1/y2
// single-buffered; 4 __syncthreads per step. LDS ~11.3 KB/block.

typedef _Float16 h8 __attribute__((ext_vector_type(8)));
typedef float f4 __attribute__((ext_vector_type(4)));

#define MFMA(a, b, c) __builtin_amdgcn_mfma_f32_16x16x32_f16(a, b, c, 0, 0, 0)

constexpr int SEQ = 256, STEPS = 255, ND = 8, SD = 4, HID = 64, G4 = 256;
constexpr int UST = 104;  // u row stride (fp16): 16B-aligned, 2-way bank alias (free)
constexpr int YST = 72;   // y row stride

__device__ __forceinline__ float sigf(float x) {
    return __builtin_amdgcn_rcpf(1.0f + __expf(-x));
}
__device__ __forceinline__ float tanh_(float x) {
    return 2.0f * __builtin_amdgcn_rcpf(1.0f + __expf(-2.0f * x)) - 1.0f;
}

__global__ __launch_bounds__(256, 2) void genlstm_kernel(
    const float* __restrict__ noise, const float* __restrict__ Wx,
    const float* __restrict__ Wh, const float* __restrict__ b,
    const float* __restrict__ W1, const float* __restrict__ b1,
    const float* __restrict__ W2, const float* __restrict__ b2,
    const float* __restrict__ W3, const float* __restrict__ b3,
    float* __restrict__ out)
{
    // u layout (K=96): [0..3]=x, [4..11]=noise, [12..15]=0, [16..79]=h, [80..95]=0
    __shared__ _Float16 Ubuf[2][16 * UST];  // 2 x 3328 B, double-buffered state
    __shared__ _Float16 Y1[16 * YST];       // 2304 B
    __shared__ _Float16 Y2[16 * YST];       // 2304 B

    const int tid  = threadIdx.x;
    const int wid  = tid >> 6;      // wave 0..3
    const int lane = tid & 63;
    const int col  = lane & 15;     // A-frag row m / B-frag col n / C col
    const int quad = lane >> 4;
    const int q8   = quad * 8;
    const int row0 = blockIdx.x * 16;
    const int n0   = wid * 16 + col;   // hidden column this lane owns

    // ---- weight B-frags -> VGPRs (fp32 -> fp16) ----
    // gate B-frag: wg[g][s][j] = Wcomb[k=32s+q8+j][64g + n0]
    h8 wg[4][3], w1f[2], w2f[2], w3f[2];
    #pragma unroll
    for (int g = 0; g < 4; ++g)
        #pragma unroll
        for (int s = 0; s < 3; ++s)
            #pragma unroll
            for (int j = 0; j < 8; ++j) {
                const int k = 32 * s + q8 + j;
                const int n = 64 * g + n0;
                float v = 0.0f;
                if (k < 12) v = Wx[k * G4 + n];
                else if (k >= 16 && k < 80) v = Wh[(k - 16) * G4 + n];
                wg[g][s][j] = (_Float16)v;
            }
    #pragma unroll
    for (int s = 0; s < 2; ++s)
        #pragma unroll
        for (int j = 0; j < 8; ++j) {
            const int k = 32 * s + q8 + j;
            w1f[s][j] = (_Float16)W1[k * HID + n0];
            w2f[s][j] = (_Float16)W2[k * HID + n0];
            w3f[s][j] = (_Float16)(col < 4 ? W3[k * SD + col] : 0.0f);
        }
    float bz[4];
    #pragma unroll
    for (int g = 0; g < 4; ++g) bz[g] = b[64 * g + n0];
    const float b1v = b1[n0], b2v = b2[n0];
    const float b3v = (col < 4) ? b3[col] : 0.0f;

    // ---- zero state buffers (x0=h0=0, pads=0) ----
    {
        _Float16* ub = &Ubuf[0][0];
        for (int i = tid; i < 2 * 16 * UST; i += 256) ub[i] = (_Float16)0.0f;
    }
    __syncthreads();
    const int nrow = lane >> 2, ncc = (lane & 3) * 2;
    if (wid == 1) {  // stage noise[:,0,:] into U0
        float2 nz = *(const float2*)(noise + ((size_t)(row0 + nrow) * SEQ + 0) * ND + ncc);
        Ubuf[0][nrow * UST + 4 + ncc] = (_Float16)nz.x;
        Ubuf[0][nrow * UST + 5 + ncc] = (_Float16)nz.y;
    }
    if (wid == 0 && lane < 16) {  // out[:,0,:] = 0
        float4 z; z.x = z.y = z.z = z.w = 0.0f;
        *(float4*)(out + ((size_t)(row0 + lane) * SEQ) * SD) = z;
    }
    __syncthreads();

    float cst[4] = {0.0f, 0.0f, 0.0f, 0.0f};  // c(row=quad*4+r, hid n0)
    float run[4] = {0.0f, 0.0f, 0.0f, 0.0f};  // cumsum (wave 0, col<4)
    int pc = 0;

    #pragma unroll 1
    for (int t = 0; t < STEPS; ++t) {
        _Float16* Uc = &Ubuf[pc][0];
        _Float16* Un = &Ubuf[pc ^ 1][0];

        // prefetch next step's noise early (t+1 <= 255 always in-bounds)
        float2 nz;
        if (wid == 1)
            nz = *(const float2*)(noise + ((size_t)(row0 + nrow) * SEQ + (t + 1)) * ND + ncc);

        // A-frags of u(t) from current buffer
        const _Float16* Umc = Uc + col * UST;
        h8 a0 = *(const h8*)(Umc + q8);
        h8 a1 = *(const h8*)(Umc + 32 + q8);
        h8 a2 = *(const h8*)(Umc + 64 + q8);

        // z = u @ [Wx;Wh] + b for this wave's 16 hid cols, all 4 gates
        f4 za[4];
        #pragma unroll
        for (int g = 0; g < 4; ++g) za[g] = (f4){bz[g], bz[g], bz[g], bz[g]};
        #pragma unroll
        for (int g = 0; g < 4; ++g) {
            za[g] = MFMA(a0, wg[g][0], za[g]);
            za[g] = MFMA(a1, wg[g][1], za[g]);
            za[g] = MFMA(a2, wg[g][2], za[g]);
        }
        #pragma unroll
        for (int r = 0; r < 4; ++r) {
            float I  = sigf(za[0][r]);
            float F  = sigf(za[1][r]);
            float G  = tanh_(za[2][r]);
            float O  = sigf(za[3][r]);
            float cn = F * cst[r] + I * G;
            cst[r] = cn;
            float H = O * tanh_(cn);
            Un[(quad * 4 + r) * UST + 16 + n0] = (_Float16)H;  // new h into next buffer
        }
        __syncthreads();  // B1: h(t) visible to all waves

        // y1 = relu(h @ W1 + b1), this wave's 16 cols
        const _Float16* Umn = Un + col * UST;
        h8 hh0 = *(const h8*)(Umn + 16 + q8);
        h8 hh1 = *(const h8*)(Umn + 48 + q8);
        f4 y1a = {b1v, b1v, b1v, b1v};
        y1a = MFMA(hh0, w1f[0], y1a);
        y1a = MFMA(hh1, w1f[1], y1a);
        #pragma unroll
        for (int r = 0; r < 4; ++r)
            Y1[(quad * 4 + r) * YST + n0] = (_Float16)fmaxf(y1a[r], 0.0f);
        __syncthreads();  // B2

        // y2 = relu(y1 @ W2 + b2)
        const _Float16* Y1m = Y1 + col * YST;
        h8 ya0 = *(const h8*)(Y1m + q8);
        h8 ya1 = *(const h8*)(Y1m + 32 + q8);
        f4 y2a = {b2v, b2v, b2v, b2v};
        y2a = MFMA(ya0, w2f[0], y2a);
        y2a = MFMA(ya1, w2f[1], y2a);
        #pragma unroll
        for (int r = 0; r < 4; ++r)
            Y2[(quad * 4 + r) * YST + n0] = (_Float16)fmaxf(y2a[r], 0.0f);
        __syncthreads();  // B3

        // x_new = y2 @ W3 + b3 (wave 0 only; N=4 padded to 16)
        if (wid == 0) {
            const _Float16* Y2m = Y2 + col * YST;
            h8 yb0 = *(const h8*)(Y2m + q8);
            h8 yb1 = *(const h8*)(Y2m + 32 + q8);
            f4 xa = {b3v, b3v, b3v, b3v};
            xa = MFMA(yb0, w3f[0], xa);
            xa = MFMA(yb1, w3f[1], xa);
            if (col < 4) {
                #pragma unroll
                for (int r = 0; r < 4; ++r) {
                    run[r] += xa[r];
                    out[((size_t)(row0 + quad * 4 + r) * SEQ + (t + 1)) * SD + col] = run[r];
                    Un[(quad * 4 + r) * UST + col] = (_Float16)xa[r];  // x for t+1
                }
            }
        }
        if (wid == 1) {  // stage noise(t+1) into next buffer
            Un[nrow * UST + 4 + ncc] = (_Float16)nz.x;
            Un[nrow * UST + 5 + ncc] = (_Float16)nz.y;
        }
        __syncthreads();  // B4: u(t+1) complete
        pc ^= 1;
    }
}

extern "C" void kernel_launch(void* const* d_in, const int* in_sizes, int n_in,
                              void* d_out, int out_size, void* d_ws, size_t ws_size,
                              hipStream_t stream) {
    genlstm_kernel<<<512, 256, 0, stream>>>(
        (const float*)d_in[0], (const float*)d_in[1], (const float*)d_in[2],
        (const float*)d_in[3], (const float*)d_in[4], (const float*)d_in[5],
        (const float*)d_in[6], (const float*)d_in[7], (const float*)d_in[8],
        (const float*)d_in[9], (float*)d_out);
}